// Round 12
// baseline (213.100 us; speedup 1.0000x reference)
//
#include <hip/hip_runtime.h>
#include <hip/hip_bf16.h>

#define N_NODES 50000
#define N_EDGES 800000
#define NUM_GRAPHS 512
#define MAXDEG 64
#define EPB 4096            // edges per phase-1 block
#define P1_BLOCKS 196       // ceil(N_EDGES / EPB)
#define NBUCK 256
#define NPB 196             // nodes per bucket; NPB*NBUCK = 50176 >= N_NODES

typedef short short8 __attribute__((ext_vector_type(8)));
typedef unsigned short u16x8 __attribute__((ext_vector_type(8)));
typedef float f32x4 __attribute__((ext_vector_type(4)));

__device__ __forceinline__ unsigned short f2bu(float f) {
    __hip_bfloat16 h = __float2bfloat16(f);
    return *reinterpret_cast<unsigned short*>(&h);
}
__device__ __forceinline__ float bu2f(unsigned short u) {
    unsigned int v = ((unsigned int)u) << 16;
    float f;
    __builtin_memcpy(&f, &v, 4);
    return f;
}

// ---- phase 1: bucket 4096 edges/block by dst/196 in LDS, write staged
//      bucket-ordered packed edges (coalesced) + per-(bucket,block) tables.
//      NO global atomics. Also zeros hs1/hs2 sentinel rows. ----
__global__ __launch_bounds__(256) void bin_k(const int* __restrict__ ei,
                                             unsigned int* __restrict__ staging,
                                             int* __restrict__ cnts_tbl,
                                             int* __restrict__ offs_tbl,
                                             unsigned short* __restrict__ hs1,
                                             unsigned short* __restrict__ hs2) {
    __shared__ unsigned int st[EPB];          // 16 KB
    __shared__ int cnt[NBUCK], cur[NBUCK], scan[NBUCK];
    int b = blockIdx.x, t = threadIdx.x;
    if (b == 0 && t < 64)
        ((unsigned int*)(hs1 + (size_t)N_NODES * 128))[t] = 0u;
    if (b == 1 && t < 64)
        ((unsigned int*)(hs2 + (size_t)N_NODES * 128))[t] = 0u;
    cnt[t] = 0;
    __syncthreads();

    int e0 = b * EPB;
    int srcv[16], dstv[16], bk[16];
#pragma unroll
    for (int k = 0; k < 16; ++k) {
        int e = e0 + k * 256 + t;
        bool ok = e < N_EDGES;
        srcv[k] = ok ? ei[e] : 0;
        dstv[k] = ok ? ei[N_EDGES + e] : 0;
        bk[k] = ok ? (dstv[k] / NPB) : -1;
        if (ok) atomicAdd(&cnt[bk[k]], 1);
    }
    __syncthreads();
    scan[t] = cnt[t];
    __syncthreads();
    for (int off = 1; off < 256; off <<= 1) {
        int u = t >= off ? scan[t - off] : 0;
        __syncthreads();
        scan[t] += u;
        __syncthreads();
    }
    int excl = scan[t] - cnt[t];
    cur[t] = excl;
    cnts_tbl[t * P1_BLOCKS + b] = cnt[t];   // [bucket][block]
    offs_tbl[t * P1_BLOCKS + b] = excl;
    __syncthreads();
#pragma unroll
    for (int k = 0; k < 16; ++k) {
        if (bk[k] >= 0) {
            int pos = atomicAdd(&cur[bk[k]], 1);
            int dl = dstv[k] - bk[k] * NPB;  // < 196, fits 8 bits
            st[pos] = (unsigned int)srcv[k] | ((unsigned int)dl << 16);
        }
    }
    __syncthreads();
    unsigned int* gout = staging + (size_t)b * EPB;
    for (int i = t; i < EPB; i += 256) gout[i] = st[i];
}

// ---- phase 2: bucket b builds padded adjacency for its 196 nodes in LDS
//      (ds atomics). Rows pre-filled with the sentinel (N_NODES) so agg can
//      read fixed 32-slot batches unconditionally. Fused: W->bf16^T. ----
__global__ __launch_bounds__(256) void adjbuild_k(const unsigned int* __restrict__ staging,
                                                  const int* __restrict__ cnts_tbl,
                                                  const int* __restrict__ offs_tbl,
                                                  unsigned short* __restrict__ adj,
                                                  int* __restrict__ cnt,
                                                  float* __restrict__ dinv,
                                                  const float* __restrict__ W1,
                                                  const float* __restrict__ W2,
                                                  unsigned short* __restrict__ W1t,
                                                  unsigned short* __restrict__ W2t) {
    int b = blockIdx.x, t = threadIdx.x;
    if (b >= NBUCK) {  // fused weight transpose-convert
        int wb = b - NBUCK;
        const float* W = wb < 64 ? W1 : W2;
        unsigned short* Wt = wb < 64 ? W1t : W2t;
        int idx = (wb & 63) * 256 + t;
        int k = idx >> 7, n = idx & 127;
        Wt[n * 128 + k] = f2bu(W[idx]);
        return;
    }
    __shared__ unsigned short adjL[NPB * MAXDEG];  // 25088 B
    __shared__ int cntL[NPB];
    __shared__ int segStart[P1_BLOCKS + 1];
    __shared__ int segOff[P1_BLOCKS];
    __shared__ int tmp[256];

    if (t < NPB) cntL[t] = 0;
    // pre-fill the whole adjacency tile with the sentinel node id
    for (int i = t; i < NPB * MAXDEG / 2; i += 256)
        ((unsigned int*)adjL)[i] = 0xC350C350u;  // N_NODES | N_NODES<<16
    int c = t < P1_BLOCKS ? cnts_tbl[b * P1_BLOCKS + t] : 0;
    if (t < P1_BLOCKS) segOff[t] = offs_tbl[b * P1_BLOCKS + t];
    tmp[t] = c;
    __syncthreads();
    for (int off = 1; off < 256; off <<= 1) {
        int u = t >= off ? tmp[t - off] : 0;
        __syncthreads();
        tmp[t] += u;
        __syncthreads();
    }
    if (t < P1_BLOCKS) segStart[t] = tmp[t] - c;  // exclusive
    if (t == 0) segStart[P1_BLOCKS] = tmp[P1_BLOCKS - 1];
    __syncthreads();

    int T = segStart[P1_BLOCKS];
    for (int f = t; f < T; f += 256) {
        int lo = 0, hi = P1_BLOCKS;
        while (hi - lo > 1) {
            int m = (lo + hi) >> 1;
            if (segStart[m] <= f) lo = m; else hi = m;
        }
        unsigned int p = staging[(size_t)lo * EPB + segOff[lo] + (f - segStart[lo])];
        int src = p & 0xFFFF;
        int dl = p >> 16;
        int slot = atomicAdd(&cntL[dl], 1);
        if (slot < MAXDEG - 1) adjL[dl * MAXDEG + slot] = (unsigned short)src;
    }
    __syncthreads();

    int nodeBase = b * NPB;
    if (t < NPB) {
        int node = nodeBase + t;
        int cc = cntL[t];
        int ec = cc < MAXDEG - 1 ? cc : MAXDEG - 1;
        adjL[t * MAXDEG + ec] = (unsigned short)node;  // self loop; rest stays sentinel
        if (node < N_NODES) {
            cnt[node] = cc;
            dinv[node] = rsqrtf((float)cc + 1.0f);
        }
    }
    __syncthreads();
    unsigned int* g = (unsigned int*)(adj + (size_t)nodeBase * MAXDEG);
    const unsigned int* l = (const unsigned int*)adjL;
    for (int i = t; i < NPB * MAXDEG / 2; i += 256) g[i] = l[i];
}

// ---- GEMM: C[r][c] = bf16( dinv[r] * sum_k A[r][k]*W[k][c] ), 128 rows/block ----
template <bool F32A>
__global__ __launch_bounds__(256) void gemm_k(const void* __restrict__ Ap,
                                              const unsigned short* __restrict__ Wt,
                                              const float* __restrict__ dinv,
                                              unsigned short* __restrict__ C) {
    __shared__ unsigned short Wl[128 * 136];
    int t = threadIdx.x;
    for (int idx = t; idx < 2048; idx += 256) {
        int n = idx >> 4, c = idx & 15;
        *(u16x8*)(Wl + n * 136 + c * 8) = *(const u16x8*)(Wt + n * 128 + c * 8);
    }
    __syncthreads();

    int wave = t >> 6, lane = t & 63, quad = lane >> 4, ln = lane & 15;
    int rb = blockIdx.x * 128 + wave * 16;

    short8 a[2][4];
#pragma unroll
    for (int mt = 0; mt < 2; ++mt) {
        int r = rb + mt * 64 + ln;
        r = r < N_NODES ? r : N_NODES - 1;
        if (F32A) {
            const float* arow = (const float*)Ap + (size_t)r * 128 + quad * 8;
#pragma unroll
            for (int ks = 0; ks < 4; ++ks) {
                float4 v0 = *(const float4*)(arow + ks * 32);
                float4 v1 = *(const float4*)(arow + ks * 32 + 4);
                short8 av;
                av[0] = (short)f2bu(v0.x); av[1] = (short)f2bu(v0.y);
                av[2] = (short)f2bu(v0.z); av[3] = (short)f2bu(v0.w);
                av[4] = (short)f2bu(v1.x); av[5] = (short)f2bu(v1.y);
                av[6] = (short)f2bu(v1.z); av[7] = (short)f2bu(v1.w);
                a[mt][ks] = av;
            }
        } else {
            const unsigned short* arow = (const unsigned short*)Ap + (size_t)r * 128 + quad * 8;
#pragma unroll
            for (int ks = 0; ks < 4; ++ks) a[mt][ks] = *(const short8*)(arow + ks * 32);
        }
    }

    f32x4 acc[2][8];
#pragma unroll
    for (int mt = 0; mt < 2; ++mt)
#pragma unroll
        for (int ct = 0; ct < 8; ++ct) acc[mt][ct] = (f32x4){0.f, 0.f, 0.f, 0.f};

#pragma unroll
    for (int ks = 0; ks < 4; ++ks)
#pragma unroll
        for (int ct = 0; ct < 8; ++ct) {
            short8 b = *(const short8*)(Wl + (ct * 16 + ln) * 136 + ks * 32 + quad * 8);
            acc[0][ct] = __builtin_amdgcn_mfma_f32_16x16x32_bf16(a[0][ks], b, acc[0][ct], 0, 0, 0);
            acc[1][ct] = __builtin_amdgcn_mfma_f32_16x16x32_bf16(a[1][ks], b, acc[1][ct], 0, 0, 0);
        }

#pragma unroll
    for (int mt = 0; mt < 2; ++mt) {
#pragma unroll
        for (int rr = 0; rr < 4; ++rr) {
            int r = rb + mt * 64 + quad * 4 + rr;
            if (r >= N_NODES) continue;
            float dv = dinv[r];
#pragma unroll
            for (int ct = 0; ct < 8; ++ct)
                C[(size_t)r * 128 + ct * 16 + ln] = f2bu(acc[mt][ct][rr] * dv);
        }
    }
}

// ---- layer-1 aggregation, half-row (64 feats = one 128B line) per wave.
//      blockIdx.y = half. lane = (slot-group l>>3, 16B sub l&7): one wide load
//      covers 8 edge rows; 4 unconditional loads cover 32 sentinel-padded
//      slots (99.98% of nodes); rare tail beyond. ----
__global__ __launch_bounds__(256) void agg1_k(const unsigned short* __restrict__ hs,
                                              const unsigned short* __restrict__ adj,
                                              const int* __restrict__ cnt,
                                              const float* __restrict__ dinv,
                                              const float* __restrict__ bias,
                                              unsigned short* __restrict__ out) {
    int wave = threadIdx.x >> 6, lane = threadIdx.x & 63;
    int node = blockIdx.x * 4 + wave;  // gridDim.x*4 == N_NODES exactly
    int fh = blockIdx.y;               // feature half: [fh*64, fh*64+64)
    int g = lane >> 3, sub = lane & 7;
    int idx = (int)adj[node * MAXDEG + lane];
    int c = cnt[node];
    int ec = c < MAXDEG - 1 ? c : MAXDEG - 1;
    int tot = ec + 1;
    const unsigned short* base = hs + fh * 64 + sub * 8;

    int s0 = __shfl(idx, g, 64);
    int s1 = __shfl(idx, 8 + g, 64);
    int s2 = __shfl(idx, 16 + g, 64);
    int s3 = __shfl(idx, 24 + g, 64);
    u16x8 v0 = *(const u16x8*)(base + (size_t)s0 * 128);
    u16x8 v1 = *(const u16x8*)(base + (size_t)s1 * 128);
    u16x8 v2 = *(const u16x8*)(base + (size_t)s2 * 128);
    u16x8 v3 = *(const u16x8*)(base + (size_t)s3 * 128);
    float acc[8];
#pragma unroll
    for (int j = 0; j < 8; ++j)
        acc[j] = (bu2f(v0[j]) + bu2f(v1[j])) + (bu2f(v2[j]) + bu2f(v3[j]));
    if (tot > 32) {  // wave-uniform, ~0.02% of nodes
        int iters = (tot + 7) >> 3;
        for (int i = 4; i < iters; ++i) {
            int s = __shfl(idx, i * 8 + g, 64);
            u16x8 v = *(const u16x8*)(base + (size_t)s * 128);
#pragma unroll
            for (int j = 0; j < 8; ++j) acc[j] += bu2f(v[j]);
        }
    }
#pragma unroll
    for (int j = 0; j < 8; ++j) {
        acc[j] += __shfl_xor(acc[j], 8, 64);
        acc[j] += __shfl_xor(acc[j], 16, 64);
        acc[j] += __shfl_xor(acc[j], 32, 64);
    }
    if (g == 0) {  // lanes 0..7 hold sub-slices of this half row
        float dv = dinv[node];
        const float* bp = bias + fh * 64 + sub * 8;
        float4 b0 = *(const float4*)bp;
        float4 b1 = *(const float4*)(bp + 4);
        u16x8 o;
        o[0] = f2bu(fmaxf(acc[0] * dv + b0.x, 0.f));
        o[1] = f2bu(fmaxf(acc[1] * dv + b0.y, 0.f));
        o[2] = f2bu(fmaxf(acc[2] * dv + b0.z, 0.f));
        o[3] = f2bu(fmaxf(acc[3] * dv + b0.w, 0.f));
        o[4] = f2bu(fmaxf(acc[4] * dv + b1.x, 0.f));
        o[5] = f2bu(fmaxf(acc[5] * dv + b1.y, 0.f));
        o[6] = f2bu(fmaxf(acc[6] * dv + b1.z, 0.f));
        o[7] = f2bu(fmaxf(acc[7] * dv + b1.w, 0.f));
        *(u16x8*)(out + (size_t)node * 128 + fh * 64 + sub * 8) = o;
    }
}

// ---- layer-2 aggregation + readout dot, half-row scheme; partial dot with
//      Wl over this half's 64 features -> pnode[fh][node]. No atomics. ----
__global__ __launch_bounds__(256) void agg_dot_k(const unsigned short* __restrict__ hs,
                                                 const unsigned short* __restrict__ adj,
                                                 const int* __restrict__ cnt,
                                                 const float* __restrict__ dinv,
                                                 const float* __restrict__ bias,
                                                 const float* __restrict__ Wl,
                                                 float* __restrict__ pnode) {
    int wave = threadIdx.x >> 6, lane = threadIdx.x & 63;
    int node = blockIdx.x * 4 + wave;
    int fh = blockIdx.y;
    int g = lane >> 3, sub = lane & 7;
    int idx = (int)adj[node * MAXDEG + lane];
    int c = cnt[node];
    int ec = c < MAXDEG - 1 ? c : MAXDEG - 1;
    int tot = ec + 1;
    const unsigned short* base = hs + fh * 64 + sub * 8;

    int s0 = __shfl(idx, g, 64);
    int s1 = __shfl(idx, 8 + g, 64);
    int s2 = __shfl(idx, 16 + g, 64);
    int s3 = __shfl(idx, 24 + g, 64);
    u16x8 v0 = *(const u16x8*)(base + (size_t)s0 * 128);
    u16x8 v1 = *(const u16x8*)(base + (size_t)s1 * 128);
    u16x8 v2 = *(const u16x8*)(base + (size_t)s2 * 128);
    u16x8 v3 = *(const u16x8*)(base + (size_t)s3 * 128);
    float acc[8];
#pragma unroll
    for (int j = 0; j < 8; ++j)
        acc[j] = (bu2f(v0[j]) + bu2f(v1[j])) + (bu2f(v2[j]) + bu2f(v3[j]));
    if (tot > 32) {
        int iters = (tot + 7) >> 3;
        for (int i = 4; i < iters; ++i) {
            int s = __shfl(idx, i * 8 + g, 64);
            u16x8 v = *(const u16x8*)(base + (size_t)s * 128);
#pragma unroll
            for (int j = 0; j < 8; ++j) acc[j] += bu2f(v[j]);
        }
    }
#pragma unroll
    for (int j = 0; j < 8; ++j) {
        acc[j] += __shfl_xor(acc[j], 8, 64);
        acc[j] += __shfl_xor(acc[j], 16, 64);
        acc[j] += __shfl_xor(acc[j], 32, 64);
    }
    float dv = dinv[node];
    const float* bp = bias + fh * 64 + sub * 8;
    const float* wp = Wl + fh * 64 + sub * 8;
    float4 b0 = *(const float4*)bp;
    float4 b1 = *(const float4*)(bp + 4);
    float4 w0 = *(const float4*)wp;
    float4 w1 = *(const float4*)(wp + 4);
    float p = fmaxf(acc[0] * dv + b0.x, 0.f) * w0.x
            + fmaxf(acc[1] * dv + b0.y, 0.f) * w0.y
            + fmaxf(acc[2] * dv + b0.z, 0.f) * w0.z
            + fmaxf(acc[3] * dv + b0.w, 0.f) * w0.w
            + fmaxf(acc[4] * dv + b1.x, 0.f) * w1.x
            + fmaxf(acc[5] * dv + b1.y, 0.f) * w1.y
            + fmaxf(acc[6] * dv + b1.z, 0.f) * w1.z
            + fmaxf(acc[7] * dv + b1.w, 0.f) * w1.w;
    p += __shfl_xor(p, 1, 64);
    p += __shfl_xor(p, 2, 64);
    p += __shfl_xor(p, 4, 64);
    if (lane == 0) pnode[fh * N_NODES + node] = p;
}

// ---- final: one wave per graph; segment-mean over the 2 half slices ----
__device__ __forceinline__ int lb(const int* a, int n, int v) {
    int lo = 0, hi = n;
    while (lo < hi) {
        int m = (lo + hi) >> 1;
        if (a[m] < v) lo = m + 1;
        else hi = m;
    }
    return lo;
}

__global__ __launch_bounds__(64) void final_k(const float* __restrict__ pnode,
                                              const int* __restrict__ batch,
                                              const float* __restrict__ bl,
                                              float* __restrict__ out) {
    int g = blockIdx.x, t = threadIdx.x;
    int lo = lb(batch, N_NODES, g), hi = lb(batch, N_NODES, g + 1);
    float s = 0.f;
    for (int r = lo + t; r < hi; r += 64)
        s += pnode[r] + pnode[N_NODES + r];
#pragma unroll
    for (int o = 32; o > 0; o >>= 1) s += __shfl_down(s, o, 64);
    if (t == 0) {
        float cf = (float)(hi - lo);
        float z = s / fmaxf(cf, 1.f) + bl[0];
        out[g] = 1.f / (1.f + expf(-z));
    }
}

extern "C" void kernel_launch(void* const* d_in, const int* in_sizes, int n_in,
                              void* d_out, int out_size, void* d_ws, size_t ws_size,
                              hipStream_t stream) {
    const float* x = (const float*)d_in[0];
    const int* ei = (const int*)d_in[1];
    const int* batch = (const int*)d_in[2];
    const float* W1 = (const float*)d_in[3];
    const float* b1 = (const float*)d_in[4];
    const float* W2 = (const float*)d_in[5];
    const float* b2 = (const float*)d_in[6];
    const float* Wl = (const float*)d_in[7];
    const float* bl = (const float*)d_in[8];
    float* out = (float*)d_out;

    char* ws = (char*)d_ws;
    unsigned int* staging = (unsigned int*)(ws + 0x0);       // 3.21 MB
    int* cnts_tbl = (int*)(ws + 0x310000);                   // 200704 B
    int* offs_tbl = (int*)(ws + 0x341000);                   // 200704 B
    unsigned short* adj = (unsigned short*)(ws + 0x372000);  // 6.42 MB
    int* cnt = (int*)(ws + 0x992000);                        // 200 KB
    float* dinv = (float*)(ws + 0x9C3000);                   // 200 KB
    unsigned short* W1t = (unsigned short*)(ws + 0x9F4000);  // 32 KB
    unsigned short* W2t = (unsigned short*)(ws + 0x9FC000);  // 32 KB
    float* pnode = (float*)(ws + 0xA04000);                  // 2 x 200 KB
    unsigned short* hs1 = (unsigned short*)(ws + 0xA68000);  // (N+1)x128 bf16
    unsigned short* h1 = (unsigned short*)(ws + 0x16A0000);  // N x 128 bf16
    unsigned short* hs2 = (unsigned short*)(ws + 0x22D8000); // (N+1)x128 bf16

    bin_k<<<P1_BLOCKS, 256, 0, stream>>>(ei, staging, cnts_tbl, offs_tbl, hs1, hs2);
    adjbuild_k<<<NBUCK + 128, 256, 0, stream>>>(staging, cnts_tbl, offs_tbl,
                                                adj, cnt, dinv, W1, W2, W1t, W2t);

    gemm_k<true><<<(N_NODES + 127) / 128, 256, 0, stream>>>(x, W1t, dinv, hs1);
    agg1_k<<<dim3(N_NODES / 4, 2), 256, 0, stream>>>(hs1, adj, cnt, dinv, b1, h1);
    gemm_k<false><<<(N_NODES + 127) / 128, 256, 0, stream>>>(h1, W2t, dinv, hs2);
    agg_dot_k<<<dim3(N_NODES / 4, 2), 256, 0, stream>>>(hs2, adj, cnt, dinv, b2, Wl, pnode);

    final_k<<<NUM_GRAPHS, 64, 0, stream>>>(pnode, batch, bl, out);
}

// Round 13
// 189.350 us; speedup vs baseline: 1.1254x; 1.1254x over previous
//
#include <hip/hip_runtime.h>
#include <hip/hip_bf16.h>

#define N_NODES 50000
#define N_EDGES 800000
#define NUM_GRAPHS 512
#define MAXDEG 64
#define EPB 4096            // edges per phase-1 block
#define P1_BLOCKS 196       // ceil(N_EDGES / EPB)
#define NBUCK 256
#define NPB 196             // nodes per bucket; NPB*NBUCK = 50176 >= N_NODES

typedef short short8 __attribute__((ext_vector_type(8)));
typedef unsigned short u16x8 __attribute__((ext_vector_type(8)));
typedef float f32x4 __attribute__((ext_vector_type(4)));

__device__ __forceinline__ unsigned short f2bu(float f) {
    __hip_bfloat16 h = __float2bfloat16(f);
    return *reinterpret_cast<unsigned short*>(&h);
}
__device__ __forceinline__ float bu2f(unsigned short u) {
    unsigned int v = ((unsigned int)u) << 16;
    float f;
    __builtin_memcpy(&f, &v, 4);
    return f;
}

// ---- phase 1: bucket 4096 edges/block by dst/196 in LDS, write staged
//      bucket-ordered packed edges (coalesced) + per-(bucket,block) tables.
//      NO global atomics. Also zeros hs1/hs2 sentinel rows. ----
__global__ __launch_bounds__(256) void bin_k(const int* __restrict__ ei,
                                             unsigned int* __restrict__ staging,
                                             int* __restrict__ cnts_tbl,
                                             int* __restrict__ offs_tbl,
                                             unsigned short* __restrict__ hs1,
                                             unsigned short* __restrict__ hs2) {
    __shared__ unsigned int st[EPB];          // 16 KB
    __shared__ int cnt[NBUCK], cur[NBUCK], scan[NBUCK];
    int b = blockIdx.x, t = threadIdx.x;
    if (b == 0 && t < 64)
        ((unsigned int*)(hs1 + (size_t)N_NODES * 128))[t] = 0u;
    if (b == 1 && t < 64)
        ((unsigned int*)(hs2 + (size_t)N_NODES * 128))[t] = 0u;
    cnt[t] = 0;
    __syncthreads();

    int e0 = b * EPB;
    int srcv[16], dstv[16], bk[16];
#pragma unroll
    for (int k = 0; k < 16; ++k) {
        int e = e0 + k * 256 + t;
        bool ok = e < N_EDGES;
        srcv[k] = ok ? ei[e] : 0;
        dstv[k] = ok ? ei[N_EDGES + e] : 0;
        bk[k] = ok ? (dstv[k] / NPB) : -1;
        if (ok) atomicAdd(&cnt[bk[k]], 1);
    }
    __syncthreads();
    scan[t] = cnt[t];
    __syncthreads();
    for (int off = 1; off < 256; off <<= 1) {
        int u = t >= off ? scan[t - off] : 0;
        __syncthreads();
        scan[t] += u;
        __syncthreads();
    }
    int excl = scan[t] - cnt[t];
    cur[t] = excl;
    cnts_tbl[t * P1_BLOCKS + b] = cnt[t];   // [bucket][block]
    offs_tbl[t * P1_BLOCKS + b] = excl;
    __syncthreads();
#pragma unroll
    for (int k = 0; k < 16; ++k) {
        if (bk[k] >= 0) {
            int pos = atomicAdd(&cur[bk[k]], 1);
            int dl = dstv[k] - bk[k] * NPB;  // < 196, fits 8 bits
            st[pos] = (unsigned int)srcv[k] | ((unsigned int)dl << 16);
        }
    }
    __syncthreads();
    unsigned int* gout = staging + (size_t)b * EPB;
    for (int i = t; i < EPB; i += 256) gout[i] = st[i];
}

// ---- phase 2: bucket b builds padded adjacency for its 196 nodes in LDS
//      (ds atomics), then writes it out coalesced. Fused: W->bf16^T. ----
__global__ __launch_bounds__(256) void adjbuild_k(const unsigned int* __restrict__ staging,
                                                  const int* __restrict__ cnts_tbl,
                                                  const int* __restrict__ offs_tbl,
                                                  unsigned short* __restrict__ adj,
                                                  int* __restrict__ cnt,
                                                  float* __restrict__ dinv,
                                                  const float* __restrict__ W1,
                                                  const float* __restrict__ W2,
                                                  unsigned short* __restrict__ W1t,
                                                  unsigned short* __restrict__ W2t) {
    int b = blockIdx.x, t = threadIdx.x;
    if (b >= NBUCK) {  // fused weight transpose-convert
        int wb = b - NBUCK;
        const float* W = wb < 64 ? W1 : W2;
        unsigned short* Wt = wb < 64 ? W1t : W2t;
        int idx = (wb & 63) * 256 + t;
        int k = idx >> 7, n = idx & 127;
        Wt[n * 128 + k] = f2bu(W[idx]);
        return;
    }
    __shared__ unsigned short adjL[NPB * MAXDEG];  // 25088 B
    __shared__ int cntL[NPB];
    __shared__ int segStart[P1_BLOCKS + 1];
    __shared__ int segOff[P1_BLOCKS];
    __shared__ int tmp[256];

    if (t < NPB) cntL[t] = 0;
    int c = t < P1_BLOCKS ? cnts_tbl[b * P1_BLOCKS + t] : 0;
    if (t < P1_BLOCKS) segOff[t] = offs_tbl[b * P1_BLOCKS + t];
    tmp[t] = c;
    __syncthreads();
    for (int off = 1; off < 256; off <<= 1) {
        int u = t >= off ? tmp[t - off] : 0;
        __syncthreads();
        tmp[t] += u;
        __syncthreads();
    }
    if (t < P1_BLOCKS) segStart[t] = tmp[t] - c;  // exclusive
    if (t == 0) segStart[P1_BLOCKS] = tmp[P1_BLOCKS - 1];
    __syncthreads();

    int T = segStart[P1_BLOCKS];
    for (int f = t; f < T; f += 256) {
        int lo = 0, hi = P1_BLOCKS;
        while (hi - lo > 1) {
            int m = (lo + hi) >> 1;
            if (segStart[m] <= f) lo = m; else hi = m;
        }
        unsigned int p = staging[(size_t)lo * EPB + segOff[lo] + (f - segStart[lo])];
        int src = p & 0xFFFF;
        int dl = p >> 16;
        int slot = atomicAdd(&cntL[dl], 1);
        if (slot < MAXDEG - 1) adjL[dl * MAXDEG + slot] = (unsigned short)src;
    }
    __syncthreads();

    int nodeBase = b * NPB;
    if (t < NPB) {
        int node = nodeBase + t;
        int cc = cntL[t];
        int ec = cc < MAXDEG - 1 ? cc : MAXDEG - 1;
        adjL[t * MAXDEG + ec] = (unsigned short)node;  // self loop
        int tot = ec + 1, tot4 = (tot + 3) & ~3;
        for (int s = tot; s < tot4; ++s) adjL[t * MAXDEG + s] = (unsigned short)N_NODES;
        if (node < N_NODES) {
            cnt[node] = cc;
            dinv[node] = rsqrtf((float)cc + 1.0f);
        }
    }
    __syncthreads();
    unsigned int* g = (unsigned int*)(adj + (size_t)nodeBase * MAXDEG);
    const unsigned int* l = (const unsigned int*)adjL;
    for (int i = t; i < NPB * MAXDEG / 2; i += 256) g[i] = l[i];
}

// ---- GEMM: C[r][c] = bf16( dinv[r] * sum_k A[r][k]*W[k][c] ), 128 rows/block ----
template <bool F32A>
__global__ __launch_bounds__(256) void gemm_k(const void* __restrict__ Ap,
                                              const unsigned short* __restrict__ Wt,
                                              const float* __restrict__ dinv,
                                              unsigned short* __restrict__ C) {
    __shared__ unsigned short Wl[128 * 136];
    int t = threadIdx.x;
    for (int idx = t; idx < 2048; idx += 256) {
        int n = idx >> 4, c = idx & 15;
        *(u16x8*)(Wl + n * 136 + c * 8) = *(const u16x8*)(Wt + n * 128 + c * 8);
    }
    __syncthreads();

    int wave = t >> 6, lane = t & 63, quad = lane >> 4, ln = lane & 15;
    int rb = blockIdx.x * 128 + wave * 16;

    short8 a[2][4];
#pragma unroll
    for (int mt = 0; mt < 2; ++mt) {
        int r = rb + mt * 64 + ln;
        r = r < N_NODES ? r : N_NODES - 1;
        if (F32A) {
            const float* arow = (const float*)Ap + (size_t)r * 128 + quad * 8;
#pragma unroll
            for (int ks = 0; ks < 4; ++ks) {
                float4 v0 = *(const float4*)(arow + ks * 32);
                float4 v1 = *(const float4*)(arow + ks * 32 + 4);
                short8 av;
                av[0] = (short)f2bu(v0.x); av[1] = (short)f2bu(v0.y);
                av[2] = (short)f2bu(v0.z); av[3] = (short)f2bu(v0.w);
                av[4] = (short)f2bu(v1.x); av[5] = (short)f2bu(v1.y);
                av[6] = (short)f2bu(v1.z); av[7] = (short)f2bu(v1.w);
                a[mt][ks] = av;
            }
        } else {
            const unsigned short* arow = (const unsigned short*)Ap + (size_t)r * 128 + quad * 8;
#pragma unroll
            for (int ks = 0; ks < 4; ++ks) a[mt][ks] = *(const short8*)(arow + ks * 32);
        }
    }

    f32x4 acc[2][8];
#pragma unroll
    for (int mt = 0; mt < 2; ++mt)
#pragma unroll
        for (int ct = 0; ct < 8; ++ct) acc[mt][ct] = (f32x4){0.f, 0.f, 0.f, 0.f};

#pragma unroll
    for (int ks = 0; ks < 4; ++ks)
#pragma unroll
        for (int ct = 0; ct < 8; ++ct) {
            short8 b = *(const short8*)(Wl + (ct * 16 + ln) * 136 + ks * 32 + quad * 8);
            acc[0][ct] = __builtin_amdgcn_mfma_f32_16x16x32_bf16(a[0][ks], b, acc[0][ct], 0, 0, 0);
            acc[1][ct] = __builtin_amdgcn_mfma_f32_16x16x32_bf16(a[1][ks], b, acc[1][ct], 0, 0, 0);
        }

#pragma unroll
    for (int mt = 0; mt < 2; ++mt) {
#pragma unroll
        for (int rr = 0; rr < 4; ++rr) {
            int r = rb + mt * 64 + quad * 4 + rr;
            if (r >= N_NODES) continue;
            float dv = dinv[r];
#pragma unroll
            for (int ct = 0; ct < 8; ++ct)
                C[(size_t)r * 128 + ct * 16 + ln] = f2bu(acc[mt][ct][rr] * dv);
        }
    }
}

// ---- layer-1 aggregation: TWO nodes per wave (8 gather loads in flight).
//      Per node: quad q reads row of edge 4i+q (16B/lane). Cross-quad shuffle
//      reduction leaves both rows in all lanes; quad0 writes node0, quad1
//      writes node1. ----
__global__ __launch_bounds__(256) void agg1_k(const unsigned short* __restrict__ hs,
                                              const unsigned short* __restrict__ adj,
                                              const int* __restrict__ cnt,
                                              const float* __restrict__ dinv,
                                              const float* __restrict__ bias,
                                              unsigned short* __restrict__ out) {
    int wave = threadIdx.x >> 6, lane = threadIdx.x & 63;
    int node0 = blockIdx.x * 8 + wave * 2;  // grid*8 == N_NODES exactly
    int node1 = node0 + 1;
    int quad = lane >> 4, fl = lane & 15;
    int idx0 = (int)adj[node0 * MAXDEG + lane];
    int idx1 = (int)adj[node1 * MAXDEG + lane];
    int c0 = cnt[node0], c1 = cnt[node1];
    int ec0 = c0 < MAXDEG - 1 ? c0 : MAXDEG - 1;
    int ec1 = c1 < MAXDEG - 1 ? c1 : MAXDEG - 1;
    int it0 = (ec0 + 4) >> 2;
    int it1 = (ec1 + 4) >> 2;
    int common = it0 < it1 ? it0 : it1;

    float a0[8], a1[8];
#pragma unroll
    for (int j = 0; j < 8; ++j) { a0[j] = 0.f; a1[j] = 0.f; }

    int i = 0;
    for (; i + 2 <= common; i += 2) {  // 4 independent wide loads
        int sA0 = __shfl(idx0, i * 4 + quad, 64);
        int sA1 = __shfl(idx0, i * 4 + 4 + quad, 64);
        int sB0 = __shfl(idx1, i * 4 + quad, 64);
        int sB1 = __shfl(idx1, i * 4 + 4 + quad, 64);
        u16x8 vA0 = *(const u16x8*)(hs + (size_t)sA0 * 128 + fl * 8);
        u16x8 vA1 = *(const u16x8*)(hs + (size_t)sA1 * 128 + fl * 8);
        u16x8 vB0 = *(const u16x8*)(hs + (size_t)sB0 * 128 + fl * 8);
        u16x8 vB1 = *(const u16x8*)(hs + (size_t)sB1 * 128 + fl * 8);
#pragma unroll
        for (int j = 0; j < 8; ++j) {
            a0[j] += bu2f(vA0[j]) + bu2f(vA1[j]);
            a1[j] += bu2f(vB0[j]) + bu2f(vB1[j]);
        }
    }
    for (; i < common; ++i) {
        int sA = __shfl(idx0, i * 4 + quad, 64);
        int sB = __shfl(idx1, i * 4 + quad, 64);
        u16x8 vA = *(const u16x8*)(hs + (size_t)sA * 128 + fl * 8);
        u16x8 vB = *(const u16x8*)(hs + (size_t)sB * 128 + fl * 8);
#pragma unroll
        for (int j = 0; j < 8; ++j) { a0[j] += bu2f(vA[j]); a1[j] += bu2f(vB[j]); }
    }
    for (; i < it0; ++i) {
        int sA = __shfl(idx0, i * 4 + quad, 64);
        u16x8 vA = *(const u16x8*)(hs + (size_t)sA * 128 + fl * 8);
#pragma unroll
        for (int j = 0; j < 8; ++j) a0[j] += bu2f(vA[j]);
    }
    for (; i < it1; ++i) {
        int sB = __shfl(idx1, i * 4 + quad, 64);
        u16x8 vB = *(const u16x8*)(hs + (size_t)sB * 128 + fl * 8);
#pragma unroll
        for (int j = 0; j < 8; ++j) a1[j] += bu2f(vB[j]);
    }

#pragma unroll
    for (int j = 0; j < 8; ++j) {
        a0[j] += __shfl_xor(a0[j], 16, 64);
        a0[j] += __shfl_xor(a0[j], 32, 64);
        a1[j] += __shfl_xor(a1[j], 16, 64);
        a1[j] += __shfl_xor(a1[j], 32, 64);
    }

    if (quad < 2) {
        int node = quad == 0 ? node0 : node1;
        const float* av = nullptr;  // select below
        float dv = dinv[node];
        float4 b0 = *(const float4*)(bias + fl * 8);
        float4 b1 = *(const float4*)(bias + fl * 8 + 4);
        float r0 = quad == 0 ? a0[0] : a1[0];
        float r1 = quad == 0 ? a0[1] : a1[1];
        float r2 = quad == 0 ? a0[2] : a1[2];
        float r3 = quad == 0 ? a0[3] : a1[3];
        float r4 = quad == 0 ? a0[4] : a1[4];
        float r5 = quad == 0 ? a0[5] : a1[5];
        float r6 = quad == 0 ? a0[6] : a1[6];
        float r7 = quad == 0 ? a0[7] : a1[7];
        u16x8 o;
        o[0] = f2bu(fmaxf(r0 * dv + b0.x, 0.f));
        o[1] = f2bu(fmaxf(r1 * dv + b0.y, 0.f));
        o[2] = f2bu(fmaxf(r2 * dv + b0.z, 0.f));
        o[3] = f2bu(fmaxf(r3 * dv + b0.w, 0.f));
        o[4] = f2bu(fmaxf(r4 * dv + b1.x, 0.f));
        o[5] = f2bu(fmaxf(r5 * dv + b1.y, 0.f));
        o[6] = f2bu(fmaxf(r6 * dv + b1.z, 0.f));
        o[7] = f2bu(fmaxf(r7 * dv + b1.w, 0.f));
        *(u16x8*)(out + (size_t)node * 128 + fl * 8) = o;
        (void)av;
    }
}

// ---- layer 2 aggregation + readout dot, TWO nodes per wave; lane 0 writes
//      both dots as one float2. No atomics. ----
__global__ __launch_bounds__(256) void agg_dot_k(const unsigned short* __restrict__ hs,
                                                 const unsigned short* __restrict__ adj,
                                                 const int* __restrict__ cnt,
                                                 const float* __restrict__ dinv,
                                                 const float* __restrict__ bias,
                                                 const float* __restrict__ Wl,
                                                 float* __restrict__ pnode) {
    int wave = threadIdx.x >> 6, lane = threadIdx.x & 63;
    int node0 = blockIdx.x * 8 + wave * 2;
    int node1 = node0 + 1;
    int quad = lane >> 4, fl = lane & 15;
    int idx0 = (int)adj[node0 * MAXDEG + lane];
    int idx1 = (int)adj[node1 * MAXDEG + lane];
    int c0 = cnt[node0], c1 = cnt[node1];
    int ec0 = c0 < MAXDEG - 1 ? c0 : MAXDEG - 1;
    int ec1 = c1 < MAXDEG - 1 ? c1 : MAXDEG - 1;
    int it0 = (ec0 + 4) >> 2;
    int it1 = (ec1 + 4) >> 2;
    int common = it0 < it1 ? it0 : it1;

    float a0[8], a1[8];
#pragma unroll
    for (int j = 0; j < 8; ++j) { a0[j] = 0.f; a1[j] = 0.f; }

    int i = 0;
    for (; i + 2 <= common; i += 2) {
        int sA0 = __shfl(idx0, i * 4 + quad, 64);
        int sA1 = __shfl(idx0, i * 4 + 4 + quad, 64);
        int sB0 = __shfl(idx1, i * 4 + quad, 64);
        int sB1 = __shfl(idx1, i * 4 + 4 + quad, 64);
        u16x8 vA0 = *(const u16x8*)(hs + (size_t)sA0 * 128 + fl * 8);
        u16x8 vA1 = *(const u16x8*)(hs + (size_t)sA1 * 128 + fl * 8);
        u16x8 vB0 = *(const u16x8*)(hs + (size_t)sB0 * 128 + fl * 8);
        u16x8 vB1 = *(const u16x8*)(hs + (size_t)sB1 * 128 + fl * 8);
#pragma unroll
        for (int j = 0; j < 8; ++j) {
            a0[j] += bu2f(vA0[j]) + bu2f(vA1[j]);
            a1[j] += bu2f(vB0[j]) + bu2f(vB1[j]);
        }
    }
    for (; i < common; ++i) {
        int sA = __shfl(idx0, i * 4 + quad, 64);
        int sB = __shfl(idx1, i * 4 + quad, 64);
        u16x8 vA = *(const u16x8*)(hs + (size_t)sA * 128 + fl * 8);
        u16x8 vB = *(const u16x8*)(hs + (size_t)sB * 128 + fl * 8);
#pragma unroll
        for (int j = 0; j < 8; ++j) { a0[j] += bu2f(vA[j]); a1[j] += bu2f(vB[j]); }
    }
    for (; i < it0; ++i) {
        int sA = __shfl(idx0, i * 4 + quad, 64);
        u16x8 vA = *(const u16x8*)(hs + (size_t)sA * 128 + fl * 8);
#pragma unroll
        for (int j = 0; j < 8; ++j) a0[j] += bu2f(vA[j]);
    }
    for (; i < it1; ++i) {
        int sB = __shfl(idx1, i * 4 + quad, 64);
        u16x8 vB = *(const u16x8*)(hs + (size_t)sB * 128 + fl * 8);
#pragma unroll
        for (int j = 0; j < 8; ++j) a1[j] += bu2f(vB[j]);
    }

#pragma unroll
    for (int j = 0; j < 8; ++j) {
        a0[j] += __shfl_xor(a0[j], 16, 64);
        a0[j] += __shfl_xor(a0[j], 32, 64);
        a1[j] += __shfl_xor(a1[j], 16, 64);
        a1[j] += __shfl_xor(a1[j], 32, 64);
    }

    float dv0 = dinv[node0], dv1 = dinv[node1];
    float4 b0 = *(const float4*)(bias + fl * 8);
    float4 b1 = *(const float4*)(bias + fl * 8 + 4);
    float4 w0 = *(const float4*)(Wl + fl * 8);
    float4 w1 = *(const float4*)(Wl + fl * 8 + 4);
    float p0 = fmaxf(a0[0] * dv0 + b0.x, 0.f) * w0.x
             + fmaxf(a0[1] * dv0 + b0.y, 0.f) * w0.y
             + fmaxf(a0[2] * dv0 + b0.z, 0.f) * w0.z
             + fmaxf(a0[3] * dv0 + b0.w, 0.f) * w0.w
             + fmaxf(a0[4] * dv0 + b1.x, 0.f) * w1.x
             + fmaxf(a0[5] * dv0 + b1.y, 0.f) * w1.y
             + fmaxf(a0[6] * dv0 + b1.z, 0.f) * w1.z
             + fmaxf(a0[7] * dv0 + b1.w, 0.f) * w1.w;
    float p1 = fmaxf(a1[0] * dv1 + b0.x, 0.f) * w0.x
             + fmaxf(a1[1] * dv1 + b0.y, 0.f) * w0.y
             + fmaxf(a1[2] * dv1 + b0.z, 0.f) * w0.z
             + fmaxf(a1[3] * dv1 + b0.w, 0.f) * w0.w
             + fmaxf(a1[4] * dv1 + b1.x, 0.f) * w1.x
             + fmaxf(a1[5] * dv1 + b1.y, 0.f) * w1.y
             + fmaxf(a1[6] * dv1 + b1.z, 0.f) * w1.z
             + fmaxf(a1[7] * dv1 + b1.w, 0.f) * w1.w;
    p0 += __shfl_xor(p0, 1, 64);
    p0 += __shfl_xor(p0, 2, 64);
    p0 += __shfl_xor(p0, 4, 64);
    p0 += __shfl_xor(p0, 8, 64);
    p1 += __shfl_xor(p1, 1, 64);
    p1 += __shfl_xor(p1, 2, 64);
    p1 += __shfl_xor(p1, 4, 64);
    p1 += __shfl_xor(p1, 8, 64);
    if (lane == 0) {
        float2 pw; pw.x = p0; pw.y = p1;
        *(float2*)(pnode + node0) = pw;  // node0 even -> 8B aligned
    }
}

// ---- final: one wave per graph; segment-mean of pnode + bias + sigmoid ----
__device__ __forceinline__ int lb(const int* a, int n, int v) {
    int lo = 0, hi = n;
    while (lo < hi) {
        int m = (lo + hi) >> 1;
        if (a[m] < v) lo = m + 1;
        else hi = m;
    }
    return lo;
}

__global__ __launch_bounds__(64) void final_k(const float* __restrict__ pnode,
                                              const int* __restrict__ batch,
                                              const float* __restrict__ bl,
                                              float* __restrict__ out) {
    int g = blockIdx.x, t = threadIdx.x;
    int lo = lb(batch, N_NODES, g), hi = lb(batch, N_NODES, g + 1);
    float s = 0.f;
    for (int r = lo + t; r < hi; r += 64) s += pnode[r];
#pragma unroll
    for (int o = 32; o > 0; o >>= 1) s += __shfl_down(s, o, 64);
    if (t == 0) {
        float cf = (float)(hi - lo);
        float z = s / fmaxf(cf, 1.f) + bl[0];
        out[g] = 1.f / (1.f + expf(-z));
    }
}

extern "C" void kernel_launch(void* const* d_in, const int* in_sizes, int n_in,
                              void* d_out, int out_size, void* d_ws, size_t ws_size,
                              hipStream_t stream) {
    const float* x = (const float*)d_in[0];
    const int* ei = (const int*)d_in[1];
    const int* batch = (const int*)d_in[2];
    const float* W1 = (const float*)d_in[3];
    const float* b1 = (const float*)d_in[4];
    const float* W2 = (const float*)d_in[5];
    const float* b2 = (const float*)d_in[6];
    const float* Wl = (const float*)d_in[7];
    const float* bl = (const float*)d_in[8];
    float* out = (float*)d_out;

    char* ws = (char*)d_ws;
    unsigned int* staging = (unsigned int*)(ws + 0x0);       // 3.21 MB
    int* cnts_tbl = (int*)(ws + 0x310000);                   // 200704 B
    int* offs_tbl = (int*)(ws + 0x341000);                   // 200704 B
    unsigned short* adj = (unsigned short*)(ws + 0x372000);  // 6.42 MB
    int* cnt = (int*)(ws + 0x992000);                        // 200 KB
    float* dinv = (float*)(ws + 0x9C3000);                   // 200 KB
    unsigned short* W1t = (unsigned short*)(ws + 0x9F4000);  // 32 KB
    unsigned short* W2t = (unsigned short*)(ws + 0x9FC000);  // 32 KB
    float* pnode = (float*)(ws + 0xA04000);                  // 200 KB
    unsigned short* hs1 = (unsigned short*)(ws + 0xA36000);  // (N+1)x128 bf16
    unsigned short* h1 = (unsigned short*)(ws + 0x1672000);  // N x 128 bf16
    unsigned short* hs2 = (unsigned short*)(ws + 0x22AE000); // (N+1)x128 bf16

    bin_k<<<P1_BLOCKS, 256, 0, stream>>>(ei, staging, cnts_tbl, offs_tbl, hs1, hs2);
    adjbuild_k<<<NBUCK + 128, 256, 0, stream>>>(staging, cnts_tbl, offs_tbl,
                                                adj, cnt, dinv, W1, W2, W1t, W2t);

    gemm_k<true><<<(N_NODES + 127) / 128, 256, 0, stream>>>(x, W1t, dinv, hs1);
    agg1_k<<<N_NODES / 8, 256, 0, stream>>>(hs1, adj, cnt, dinv, b1, h1);
    gemm_k<false><<<(N_NODES + 127) / 128, 256, 0, stream>>>(h1, W2t, dinv, hs2);
    agg_dot_k<<<N_NODES / 8, 256, 0, stream>>>(hs2, adj, cnt, dinv, b2, Wl, pnode);

    final_k<<<NUM_GRAPHS, 64, 0, stream>>>(pnode, batch, bl, out);
}